// Round 1
// baseline (550.147 us; speedup 1.0000x reference)
//
#include <hip/hip_runtime.h>
#include <hip/hip_bf16.h>

// MessagePassing: out = (A / rowsum|A|) @ X @ W + b
//   A [8192,8192] f32, X [8192,512] f32, W [512,256] f32, b [256] f32 -> out [8192,256] f32
//
// Plan:
//   k0: transpose+cvt  X -> XT bf16 [512][8192],  W -> WT bf16 [256][512]   (ws)
//   k1: S = diag(1/||A_i||_1) * (A @ X) as bf16 [8192][512]  (rowsum fused into A staging)
//   k2: out = S @ W + bias  (f32)
// ws layout: XT @0 (8 MiB), WT @8 MiB (256 KiB), Sb @8.25 MiB (8 MiB) -> 16.25 MiB total.

typedef __attribute__((ext_vector_type(8))) __bf16 bf16x8;
typedef __attribute__((ext_vector_type(4))) float f32x4;

#define AS1 __attribute__((address_space(1)))
#define AS3 __attribute__((address_space(3)))

__device__ __forceinline__ void async_load16(const void* g, void* l) {
  // gfx950 direct global->LDS DMA, 16B/lane; LDS dest must be uniform-base + lane*16
  __builtin_amdgcn_global_load_lds((const AS1 void*)g, (AS3 void*)l, 16, 0, 0);
}

// ---------------- kernel 0: 64x64 tiled transpose + f32->bf16 ----------------
__global__ __launch_bounds__(256) void transpose_cvt_kernel(
    const float* __restrict__ src, __hip_bfloat16* __restrict__ dst, int R, int C) {
  __shared__ float tile[64][65];  // +1 pad: conflict-free column reads
  const int t = threadIdx.x;
  const int nrb = R >> 6;
  const int rb = blockIdx.x % nrb, cb = blockIdx.x / nrb;
  const int r0 = rb * 64, c0 = cb * 64;
  const int lr = t >> 4, lc4 = (t & 15) * 4;
#pragma unroll
  for (int p = 0; p < 4; ++p) {
    const int r = p * 16 + lr;
    const f32x4 v = *(const f32x4*)(src + (size_t)(r0 + r) * C + c0 + lc4);
    tile[r][lc4 + 0] = v[0]; tile[r][lc4 + 1] = v[1];
    tile[r][lc4 + 2] = v[2]; tile[r][lc4 + 3] = v[3];
  }
  __syncthreads();
#pragma unroll
  for (int i = 0; i < 16; ++i) {
    const int idx = i * 256 + t;
    const int n = idx >> 6, k = idx & 63;  // per wave: n fixed, k=lane -> 128B contiguous stores
    dst[(size_t)(c0 + n) * R + r0 + k] = __float2bfloat16(tile[k][n]);
  }
}

// ---------------- kernel 1: S = (A @ X) / rownorm, bf16 out ----------------
// BM=128, BN=128, BK=64, 256 threads (4 waves, 2x2), wave-tile 64x64 (4x4 MFMA tiles)
// A: global f32 -> regs -> (rowsum, cvt bf16) -> ds_write, XOR-swizzled chunks
// X: XT bf16 via global_load_lds, source-address XOR swizzle
__global__ __launch_bounds__(256) void gemm1_kernel(
    const float* __restrict__ A,            // [8192][8192]
    const __hip_bfloat16* __restrict__ XT,  // [512][8192]
    __hip_bfloat16* __restrict__ Sb)        // [8192][512]
{
  __shared__ char smem[65536];
  char* Abase = smem;             // [2][128 rows][128 B], chunk P = G ^ (m&7)
  char* Xbase = smem + 32768;     // [2][128 n   ][128 B], chunk P = G ^ (n&7)
  float* rsmem = (float*)Xbase;   // aliases Xbuf[0]; safe: last compute (kt=127) uses buf1

  const int t = threadIdx.x;
  const int wave = t >> 6, lane = t & 63;
  const int quad = lane >> 4, l16 = lane & 15;

  // XCD swizzle: XCD = blockIdx%8 heuristic; give each XCD 8 row-blocks x all 4 col-blocks
  // so the 4x A re-read is served by that XCD's L2 (working set ~256KB << 4MiB).
  const int b = blockIdx.x;
  const int xcd = b & 7, s = b >> 3;
  const int rb = xcd * 8 + (s >> 2), cb = s & 3;
  const int r0 = rb * 128, c0 = cb * 128;

  const int wm = wave & 1, wn = wave >> 1;

  f32x4 acc[4][4] = {};
  float rs = 0.0f;  // sum |A| over this thread's half-rows (fp32, exact)

  // A staging: thread -> row am = t>>1, k-half (t&1)*32 (32 floats / iter)
  const int am = t >> 1;
  const int akc = (t & 1) * 4;  // first bf16-chunk index (chunk = 8 bf16 = 16B)
  const float* ap = A + (size_t)(r0 + am) * 8192 + (t & 1) * 32;
  char* aw_base = Abase + am * 128;

  f32x4 areg[8];
#pragma unroll
  for (int i = 0; i < 8; ++i) areg[i] = *(const f32x4*)(ap + i * 4);

  // X prologue (kt=0 -> buf0)
#pragma unroll
  for (int i = 0; i < 4; ++i) {
    const int slot = i * 256 + t;
    const int n = slot >> 3;
    const int G = (slot & 7) ^ (n & 7);
    async_load16(XT + (size_t)(c0 + n) * 8192 + G * 8, Xbase + slot * 16);
  }

  int cur = 0;
#pragma unroll 2
  for (int kt = 0; kt < 128; ++kt) {
    {  // stage A(kt) into Abuf[cur]: rowsum + cvt + swizzled ds_write_b128
      char* aw = aw_base + cur * 16384;
#pragma unroll
      for (int i = 0; i < 4; ++i) {
        const f32x4 e = areg[i * 2], o = areg[i * 2 + 1];
        rs += fabsf(e[0]) + fabsf(e[1]) + fabsf(e[2]) + fabsf(e[3]) +
              fabsf(o[0]) + fabsf(o[1]) + fabsf(o[2]) + fabsf(o[3]);
        bf16x8 v;
        v[0] = (__bf16)e[0]; v[1] = (__bf16)e[1]; v[2] = (__bf16)e[2]; v[3] = (__bf16)e[3];
        v[4] = (__bf16)o[0]; v[5] = (__bf16)o[1]; v[6] = (__bf16)o[2]; v[7] = (__bf16)o[3];
        const int P = (akc + i) ^ (am & 7);
        *(bf16x8*)(aw + P * 16) = v;
      }
    }
    __syncthreads();  // Abuf[cur]+Xbuf[cur] ready; all waves past compute(kt-1)

    if (kt < 127) {  // prefetch kt+1 (A->regs async, X->other LDS buf async)
      const float* apk = ap + (kt + 1) * 64;
#pragma unroll
      for (int i = 0; i < 8; ++i) areg[i] = *(const f32x4*)(apk + i * 4);
#pragma unroll
      for (int i = 0; i < 4; ++i) {
        const int slot = i * 256 + t;
        const int n = slot >> 3;
        const int G = (slot & 7) ^ (n & 7);
        async_load16(XT + (size_t)(c0 + n) * 8192 + (kt + 1) * 64 + G * 8,
                     Xbase + (cur ^ 1) * 16384 + slot * 16);
      }
    }

    {  // compute: 16 ds_read_b128 + 32 MFMA per wave
      const char* ab = Abase + cur * 16384;
      const char* xb = Xbase + cur * 16384;
      bf16x8 af[4][2];
#pragma unroll
      for (int rt = 0; rt < 4; ++rt) {
        const int row = wm * 64 + rt * 16 + l16;
#pragma unroll
        for (int kb = 0; kb < 2; ++kb) {
          const int ch = (kb * 4 + quad) ^ (row & 7);
          af[rt][kb] = *(const bf16x8*)(ab + row * 128 + ch * 16);
        }
      }
#pragma unroll
      for (int ct = 0; ct < 4; ++ct) {
        const int nrow = wn * 64 + ct * 16 + l16;
#pragma unroll
        for (int kb = 0; kb < 2; ++kb) {
          const int ch = (kb * 4 + quad) ^ (nrow & 7);
          const bf16x8 bfr = *(const bf16x8*)(xb + nrow * 128 + ch * 16);
#pragma unroll
          for (int rt = 0; rt < 4; ++rt)
            acc[rt][ct] = __builtin_amdgcn_mfma_f32_16x16x32_bf16(
                af[rt][kb], bfr, acc[rt][ct], 0, 0, 0);
        }
      }
    }
    cur ^= 1;
  }

  // epilogue: rowsum reduce (thread pairs), scale, store bf16
  rsmem[t] = rs;  // aliased region disjoint from Xbuf[1] used by compute(127)
  __syncthreads();
#pragma unroll
  for (int rt = 0; rt < 4; ++rt) {
#pragma unroll
    for (int r = 0; r < 4; ++r) {
      const int row_l = wm * 64 + rt * 16 + quad * 4 + r;  // C/D: row=(lane>>4)*4+reg
      const float nrm = rsmem[2 * row_l] + rsmem[2 * row_l + 1];
      const float inv = 1.0f / fmaxf(nrm, 1e-12f);
#pragma unroll
      for (int ct = 0; ct < 4; ++ct) {
        const int col_l = wn * 64 + ct * 16 + l16;  // C/D: col=lane&15
        Sb[(size_t)(r0 + row_l) * 512 + c0 + col_l] =
            __float2bfloat16(acc[rt][ct][r] * inv);
      }
    }
  }
}

// ---------------- kernel 2: out = S @ W + bias ----------------
// BM=64, BN=128, BK=64, 256 threads (4 waves 2x2), wave-tile 32x64, K-steps=8
__global__ __launch_bounds__(256) void gemm2_kernel(
    const __hip_bfloat16* __restrict__ Sb,  // [8192][512]
    const __hip_bfloat16* __restrict__ WT,  // [256][512]
    const float* __restrict__ bias,         // [256]
    float* __restrict__ Out)                // [8192][256]
{
  __shared__ char smem[49152];
  char* Sbase = smem;            // [2][64][128B]
  char* Wbase = smem + 16384;    // [2][128][128B]

  const int t = threadIdx.x;
  const int wave = t >> 6, lane = t & 63;
  const int quad = lane >> 4, l16 = lane & 15;

  const int b = blockIdx.x;
  const int xcd = b & 7, s = b >> 3;
  const int rb = xcd * 16 + (s >> 1), cb = s & 1;
  const int r0 = rb * 64, c0 = cb * 128;

  const int wm = wave & 1, wn = wave >> 1;

  f32x4 acc[2][4] = {};

  auto issue = [&](int buf, int kt) {
#pragma unroll
    for (int i = 0; i < 2; ++i) {  // S tile: 64 rows x 8 chunks
      const int slot = i * 256 + t;
      const int m = slot >> 3;
      const int G = (slot & 7) ^ (m & 7);
      async_load16(Sb + (size_t)(r0 + m) * 512 + kt * 64 + G * 8,
                   Sbase + buf * 8192 + slot * 16);
    }
#pragma unroll
    for (int i = 0; i < 4; ++i) {  // W^T tile: 128 n x 8 chunks
      const int slot = i * 256 + t;
      const int n = slot >> 3;
      const int G = (slot & 7) ^ (n & 7);
      async_load16(WT + (size_t)(c0 + n) * 512 + kt * 64 + G * 8,
                   Wbase + buf * 16384 + slot * 16);
    }
  };

  issue(0, 0);
  int cur = 0;
#pragma unroll 2
  for (int kt = 0; kt < 8; ++kt) {
    __syncthreads();
    if (kt < 7) issue(cur ^ 1, kt + 1);
    const char* sb = Sbase + cur * 8192;
    const char* wb = Wbase + cur * 16384;
    bf16x8 af[2][2];
#pragma unroll
    for (int rt = 0; rt < 2; ++rt) {
      const int row = wm * 32 + rt * 16 + l16;
#pragma unroll
      for (int kb = 0; kb < 2; ++kb) {
        const int ch = (kb * 4 + quad) ^ (row & 7);
        af[rt][kb] = *(const bf16x8*)(sb + row * 128 + ch * 16);
      }
    }
#pragma unroll
    for (int ct = 0; ct < 4; ++ct) {
      const int nrow = wn * 64 + ct * 16 + l16;
#pragma unroll
      for (int kb = 0; kb < 2; ++kb) {
        const int ch = (kb * 4 + quad) ^ (nrow & 7);
        const bf16x8 bfr = *(const bf16x8*)(wb + nrow * 128 + ch * 16);
#pragma unroll
        for (int rt = 0; rt < 2; ++rt)
          acc[rt][ct] = __builtin_amdgcn_mfma_f32_16x16x32_bf16(
              af[rt][kb], bfr, acc[rt][ct], 0, 0, 0);
      }
    }
    cur ^= 1;
  }

#pragma unroll
  for (int rt = 0; rt < 2; ++rt) {
#pragma unroll
    for (int r = 0; r < 4; ++r) {
      const int row_l = wm * 32 + rt * 16 + quad * 4 + r;
#pragma unroll
      for (int ct = 0; ct < 4; ++ct) {
        const int col_l = wn * 64 + ct * 16 + l16;
        Out[(size_t)(r0 + row_l) * 256 + c0 + col_l] =
            acc[rt][ct][r] + bias[c0 + col_l];
      }
    }
  }
}

extern "C" void kernel_launch(void* const* d_in, const int* in_sizes, int n_in,
                              void* d_out, int out_size, void* d_ws, size_t ws_size,
                              hipStream_t stream) {
  const float* A    = (const float*)d_in[0];  // adjacency [8192][8192]
  const float* Xf   = (const float*)d_in[1];  // input_feature [8192][512]
  const float* Wf   = (const float*)d_in[2];  // weight [512][256]
  const float* bias = (const float*)d_in[3];  // bias [256]
  float* Out = (float*)d_out;

  char* ws = (char*)d_ws;  // needs 16.25 MiB
  __hip_bfloat16* XT = (__hip_bfloat16*)ws;                       // [512][8192]
  __hip_bfloat16* WT = (__hip_bfloat16*)(ws + 8388608);           // [256][512]
  __hip_bfloat16* Sb = (__hip_bfloat16*)(ws + 8388608 + 262144);  // [8192][512]

  transpose_cvt_kernel<<<1024, 256, 0, stream>>>(Xf, XT, 8192, 512);
  transpose_cvt_kernel<<<32, 256, 0, stream>>>(Wf, WT, 512, 256);
  gemm1_kernel<<<256, 256, 0, stream>>>(A, XT, Sb);
  gemm2_kernel<<<256, 256, 0, stream>>>(Sb, WT, bias, Out);
}

// Round 2
// 520.621 us; speedup vs baseline: 1.0567x; 1.0567x over previous
//
#include <hip/hip_runtime.h>
#include <hip/hip_bf16.h>

// MessagePassing: out = (A / rowsum|A|) @ X @ W + b
//   A [8192,8192] f32, X [8192,512] f32, W [512,256] f32, b [256] f32 -> out [8192,256] f32
//
// Plan:
//   k0: transpose+cvt  X -> XT bf16 [512][8192],  W -> WT bf16 [256][512]   (ws)
//   k1: split-K x2 GEMM: P[ks] = A[:, ksK:(ks+1)K] @ X[ksK:...]  (bf16 partials)
//       + per-K-half rowsums RS[ks][8192]   (fp32, fused into A staging)
//   k2: combine: Sb = (P0+P1) * 1/max(rs0+rs1, eps)   (bf16; Sb aliases P0)
//   k3: out = Sb @ W + bias  (f32)
//
// R1 post-mortem: grid 256 = 1 block/CU = 1 wave/SIMD -> latency-bound
// (Occupancy 11.8%, MfmaUtil 10%, 5060 cyc/iter). Split-K x2 -> 512 blocks,
// 2 blocks/CU, independent barriers interleave.

typedef __attribute__((ext_vector_type(8))) __bf16 bf16x8;
typedef __attribute__((ext_vector_type(4))) float f32x4;

#define AS1 __attribute__((address_space(1)))
#define AS3 __attribute__((address_space(3)))

__device__ __forceinline__ void async_load16(const void* g, void* l) {
  // gfx950 direct global->LDS DMA, 16B/lane; LDS dest must be uniform-base + lane*16
  __builtin_amdgcn_global_load_lds((const AS1 void*)g, (AS3 void*)l, 16, 0, 0);
}

// ---------------- kernel 0: 64x64 tiled transpose + f32->bf16 ----------------
__global__ __launch_bounds__(256) void transpose_cvt_kernel(
    const float* __restrict__ src, __hip_bfloat16* __restrict__ dst, int R, int C) {
  __shared__ float tile[64][65];  // +1 pad: conflict-free column reads
  const int t = threadIdx.x;
  const int nrb = R >> 6;
  const int rb = blockIdx.x % nrb, cb = blockIdx.x / nrb;
  const int r0 = rb * 64, c0 = cb * 64;
  const int lr = t >> 4, lc4 = (t & 15) * 4;
#pragma unroll
  for (int p = 0; p < 4; ++p) {
    const int r = p * 16 + lr;
    const f32x4 v = *(const f32x4*)(src + (size_t)(r0 + r) * C + c0 + lc4);
    tile[r][lc4 + 0] = v[0]; tile[r][lc4 + 1] = v[1];
    tile[r][lc4 + 2] = v[2]; tile[r][lc4 + 3] = v[3];
  }
  __syncthreads();
#pragma unroll
  for (int i = 0; i < 16; ++i) {
    const int idx = i * 256 + t;
    const int n = idx >> 6, k = idx & 63;  // per wave: n fixed, k=lane -> 128B contiguous stores
    dst[(size_t)(c0 + n) * R + r0 + k] = __float2bfloat16(tile[k][n]);
  }
}

// ---------------- kernel 1: split-K partial GEMM, bf16 partials ----------------
// BM=128, BN=128, BK=64, 256 threads (4 waves, 2x2), wave-tile 64x64 (4x4 MFMA tiles)
// grid 512 = 64 rb x 4 cb x 2 ks -> 2 blocks/CU
__global__ __launch_bounds__(256) void gemm1_kernel(
    const float* __restrict__ A,            // [8192][8192]
    const __hip_bfloat16* __restrict__ XT,  // [512][8192]
    __hip_bfloat16* __restrict__ P0,        // [8192][512] partial ks=0
    __hip_bfloat16* __restrict__ P1,        // [8192][512] partial ks=1
    float* __restrict__ RS)                 // [2][8192] partial rowsums
{
  __shared__ char smem[65536];
  char* Abase = smem;             // [2][128 rows][128 B], chunk P = G ^ (m&7)
  char* Xbase = smem + 32768;     // [2][128 n   ][128 B], chunk P = G ^ (n&7)
  float* rsmem = (float*)Xbase;   // aliases Xbuf[0]; safe: last compute (kt=63) uses buf1

  const int t = threadIdx.x;
  const int wave = t >> 6, lane = t & 63;
  const int quad = lane >> 4, l16 = lane & 15;

  // XCD swizzle: 4 cb-siblings of each (rb,ks) co-resident on one XCD so the
  // 4x A re-read is L2-served. b&7 = XCD heuristic.
  const int b = blockIdx.x;
  const int xcd = b & 7, s = b >> 3;          // s in 0..63
  const int rb = xcd * 8 + (s >> 3);          // 0..63
  const int cb = s & 3;                       // 0..3
  const int ks = (s >> 2) & 1;                // 0..1
  const int r0 = rb * 128, c0 = cb * 128;
  const int k0 = ks * 4096;

  const int wm = wave & 1, wn = wave >> 1;

  f32x4 acc[4][4] = {};
  float rs = 0.0f;  // sum |A| over this thread's half-rows, this K-half (fp32)

  // A staging: thread -> row am = t>>1, k-half (t&1)*32 (32 floats / iter)
  const int am = t >> 1;
  const int akc = (t & 1) * 4;  // first bf16-chunk index (chunk = 8 bf16 = 16B)
  const float* ap = A + (size_t)(r0 + am) * 8192 + k0 + (t & 1) * 32;
  char* aw_base = Abase + am * 128;

  f32x4 areg[8];
#pragma unroll
  for (int i = 0; i < 8; ++i) areg[i] = *(const f32x4*)(ap + i * 4);

  // X prologue (kt=0 -> buf0)
#pragma unroll
  for (int i = 0; i < 4; ++i) {
    const int slot = i * 256 + t;
    const int n = slot >> 3;
    const int G = (slot & 7) ^ (n & 7);
    async_load16(XT + (size_t)(c0 + n) * 8192 + k0 + G * 8, Xbase + slot * 16);
  }

  int cur = 0;
#pragma unroll 2
  for (int kt = 0; kt < 64; ++kt) {
    {  // stage A(kt) into Abuf[cur]: rowsum + cvt + swizzled ds_write_b128
      char* aw = aw_base + cur * 16384;
#pragma unroll
      for (int i = 0; i < 4; ++i) {
        const f32x4 e = areg[i * 2], o = areg[i * 2 + 1];
        rs += fabsf(e[0]) + fabsf(e[1]) + fabsf(e[2]) + fabsf(e[3]) +
              fabsf(o[0]) + fabsf(o[1]) + fabsf(o[2]) + fabsf(o[3]);
        bf16x8 v;
        v[0] = (__bf16)e[0]; v[1] = (__bf16)e[1]; v[2] = (__bf16)e[2]; v[3] = (__bf16)e[3];
        v[4] = (__bf16)o[0]; v[5] = (__bf16)o[1]; v[6] = (__bf16)o[2]; v[7] = (__bf16)o[3];
        const int P = (akc + i) ^ (am & 7);
        *(bf16x8*)(aw + P * 16) = v;
      }
    }
    __syncthreads();  // Abuf[cur]+Xbuf[cur] ready; all waves past compute(kt-1)

    if (kt < 63) {  // prefetch kt+1 (A->regs, X->other LDS buf async)
      const float* apk = ap + (kt + 1) * 64;
#pragma unroll
      for (int i = 0; i < 8; ++i) areg[i] = *(const f32x4*)(apk + i * 4);
#pragma unroll
      for (int i = 0; i < 4; ++i) {
        const int slot = i * 256 + t;
        const int n = slot >> 3;
        const int G = (slot & 7) ^ (n & 7);
        async_load16(XT + (size_t)(c0 + n) * 8192 + k0 + (kt + 1) * 64 + G * 8,
                     Xbase + (cur ^ 1) * 16384 + slot * 16);
      }
    }

    {  // compute: 16 ds_read_b128 + 32 MFMA per wave
      const char* ab = Abase + cur * 16384;
      const char* xb = Xbase + cur * 16384;
      bf16x8 af[4][2];
#pragma unroll
      for (int rt = 0; rt < 4; ++rt) {
        const int row = wm * 64 + rt * 16 + l16;
#pragma unroll
        for (int kb = 0; kb < 2; ++kb) {
          const int ch = (kb * 4 + quad) ^ (row & 7);
          af[rt][kb] = *(const bf16x8*)(ab + row * 128 + ch * 16);
        }
      }
#pragma unroll
      for (int ct = 0; ct < 4; ++ct) {
        const int nrow = wn * 64 + ct * 16 + l16;
#pragma unroll
        for (int kb = 0; kb < 2; ++kb) {
          const int ch = (kb * 4 + quad) ^ (nrow & 7);
          const bf16x8 bfr = *(const bf16x8*)(xb + nrow * 128 + ch * 16);
#pragma unroll
          for (int rt = 0; rt < 4; ++rt)
            acc[rt][ct] = __builtin_amdgcn_mfma_f32_16x16x32_bf16(
                af[rt][kb], bfr, acc[rt][ct], 0, 0, 0);
        }
      }
    }
    cur ^= 1;
  }

  // epilogue: rowsum reduce (thread pairs), write partial rowsums + raw partials
  rsmem[t] = rs;  // buf0 region, disjoint from Xbuf[1] used by compute(63)
  __syncthreads();
  if (cb == 0 && t < 128) {
    RS[ks * 8192 + r0 + t] = rsmem[2 * t] + rsmem[2 * t + 1];
  }
  __hip_bfloat16* Pk = ks ? P1 : P0;
#pragma unroll
  for (int rt = 0; rt < 4; ++rt) {
#pragma unroll
    for (int r = 0; r < 4; ++r) {
      const int row_l = wm * 64 + rt * 16 + quad * 4 + r;  // C/D: row=(lane>>4)*4+reg
#pragma unroll
      for (int ct = 0; ct < 4; ++ct) {
        const int col_l = wn * 64 + ct * 16 + l16;  // C/D: col=lane&15
        Pk[(size_t)(r0 + row_l) * 512 + c0 + col_l] = __float2bfloat16(acc[rt][ct][r]);
      }
    }
  }
}

// ---------------- kernel 2: combine partials -> normalized S (bf16) ----------------
// Sb may alias P0 (elementwise read-then-write, one thread per element group)
__global__ __launch_bounds__(256) void combine_kernel(
    const __hip_bfloat16* __restrict__ P0, const __hip_bfloat16* __restrict__ P1,
    const float* __restrict__ RS, __hip_bfloat16* __restrict__ Sb) {
  const int idx = blockIdx.x * 256 + threadIdx.x;  // 8 cols per thread
  const int row = idx >> 6;
  const int c = (idx & 63) * 8;
  const float inv = 1.0f / fmaxf(RS[row] + RS[8192 + row], 1e-12f);
  const size_t off = (size_t)row * 512 + c;
  const bf16x8 p0 = *(const bf16x8*)(P0 + off);
  const bf16x8 p1 = *(const bf16x8*)(P1 + off);
  bf16x8 o;
#pragma unroll
  for (int i = 0; i < 8; ++i)
    o[i] = (__bf16)(((float)p0[i] + (float)p1[i]) * inv);
  *(bf16x8*)(Sb + off) = o;
}

// ---------------- kernel 3: out = S @ W + bias ----------------
// BM=64, BN=128, BK=64, 256 threads (4 waves 2x2), wave-tile 32x64, K-steps=8
__global__ __launch_bounds__(256) void gemm2_kernel(
    const __hip_bfloat16* __restrict__ Sb,  // [8192][512]
    const __hip_bfloat16* __restrict__ WT,  // [256][512]
    const float* __restrict__ bias,         // [256]
    float* __restrict__ Out)                // [8192][256]
{
  __shared__ char smem[49152];
  char* Sbase = smem;            // [2][64][128B]
  char* Wbase = smem + 16384;    // [2][128][128B]

  const int t = threadIdx.x;
  const int wave = t >> 6, lane = t & 63;
  const int quad = lane >> 4, l16 = lane & 15;

  const int b = blockIdx.x;
  const int xcd = b & 7, s = b >> 3;
  const int rb = xcd * 16 + (s >> 1), cb = s & 1;
  const int r0 = rb * 64, c0 = cb * 128;

  const int wm = wave & 1, wn = wave >> 1;

  f32x4 acc[2][4] = {};

  auto issue = [&](int buf, int kt) {
#pragma unroll
    for (int i = 0; i < 2; ++i) {  // S tile: 64 rows x 8 chunks
      const int slot = i * 256 + t;
      const int m = slot >> 3;
      const int G = (slot & 7) ^ (m & 7);
      async_load16(Sb + (size_t)(r0 + m) * 512 + kt * 64 + G * 8,
                   Sbase + buf * 8192 + slot * 16);
    }
#pragma unroll
    for (int i = 0; i < 4; ++i) {  // W^T tile: 128 n x 8 chunks
      const int slot = i * 256 + t;
      const int n = slot >> 3;
      const int G = (slot & 7) ^ (n & 7);
      async_load16(WT + (size_t)(c0 + n) * 512 + kt * 64 + G * 8,
                   Wbase + buf * 16384 + slot * 16);
    }
  };

  issue(0, 0);
  int cur = 0;
#pragma unroll 2
  for (int kt = 0; kt < 8; ++kt) {
    __syncthreads();
    if (kt < 7) issue(cur ^ 1, kt + 1);
    const char* sb = Sbase + cur * 8192;
    const char* wb = Wbase + cur * 16384;
    bf16x8 af[2][2];
#pragma unroll
    for (int rt = 0; rt < 2; ++rt) {
      const int row = wm * 32 + rt * 16 + l16;
#pragma unroll
      for (int kb = 0; kb < 2; ++kb) {
        const int ch = (kb * 4 + quad) ^ (row & 7);
        af[rt][kb] = *(const bf16x8*)(sb + row * 128 + ch * 16);
      }
    }
#pragma unroll
    for (int ct = 0; ct < 4; ++ct) {
      const int nrow = wn * 64 + ct * 16 + l16;
#pragma unroll
      for (int kb = 0; kb < 2; ++kb) {
        const int ch = (kb * 4 + quad) ^ (nrow & 7);
        const bf16x8 bfr = *(const bf16x8*)(wb + nrow * 128 + ch * 16);
#pragma unroll
        for (int rt = 0; rt < 2; ++rt)
          acc[rt][ct] = __builtin_amdgcn_mfma_f32_16x16x32_bf16(
              af[rt][kb], bfr, acc[rt][ct], 0, 0, 0);
      }
    }
    cur ^= 1;
  }

#pragma unroll
  for (int rt = 0; rt < 2; ++rt) {
#pragma unroll
    for (int r = 0; r < 4; ++r) {
      const int row_l = wm * 32 + rt * 16 + quad * 4 + r;
#pragma unroll
      for (int ct = 0; ct < 4; ++ct) {
        const int col_l = wn * 64 + ct * 16 + l16;
        Out[(size_t)(r0 + row_l) * 256 + c0 + col_l] =
            acc[rt][ct][r] + bias[c0 + col_l];
      }
    }
  }
}

extern "C" void kernel_launch(void* const* d_in, const int* in_sizes, int n_in,
                              void* d_out, int out_size, void* d_ws, size_t ws_size,
                              hipStream_t stream) {
  const float* A    = (const float*)d_in[0];  // adjacency [8192][8192]
  const float* Xf   = (const float*)d_in[1];  // input_feature [8192][512]
  const float* Wf   = (const float*)d_in[2];  // weight [512][256]
  const float* bias = (const float*)d_in[3];  // bias [256]
  float* Out = (float*)d_out;

  char* ws = (char*)d_ws;  // needs ~24.3 MiB
  __hip_bfloat16* XT = (__hip_bfloat16*)ws;                        // [512][8192]  8 MiB
  __hip_bfloat16* WT = (__hip_bfloat16*)(ws + 8388608);            // [256][512]   256 KiB
  __hip_bfloat16* P0 = (__hip_bfloat16*)(ws + 8650752);           // [8192][512]  8 MiB (aliased as Sb)
  __hip_bfloat16* P1 = (__hip_bfloat16*)(ws + 17039360);          // [8192][512]  8 MiB
  float*          RS = (float*)(ws + 25427968);                    // [2][8192]    64 KiB
  __hip_bfloat16* Sb = P0;  // combine writes in place (elementwise-safe)

  transpose_cvt_kernel<<<1024, 256, 0, stream>>>(Xf, XT, 8192, 512);
  transpose_cvt_kernel<<<32, 256, 0, stream>>>(Wf, WT, 512, 256);
  gemm1_kernel<<<512, 256, 0, stream>>>(A, XT, P0, P1, RS);
  combine_kernel<<<16384, 256, 0, stream>>>(P0, P1, RS, Sb);
  gemm2_kernel<<<256, 256, 0, stream>>>(Sb, WT, bias, Out);
}

// Round 3
// 514.334 us; speedup vs baseline: 1.0696x; 1.0122x over previous
//
#include <hip/hip_runtime.h>
#include <hip/hip_bf16.h>

// MessagePassing: out = (A / rowsum|A|) @ X @ W + b
//   A [8192,8192] f32, X [8192,512] f32, W [512,256] f32, b [256] f32 -> out [8192,256] f32
//
// R2 post-mortem: 2 blocks/CU (Occ 20.9%) still 80% stalled; lever = concurrency.
// R3: BK=32 (LDS 32KB) + split-K x4 (grid 1024) -> 4 blocks/CU. Partials via
// f32 atomicAdd into Sacc (16 MiB, memset 0), rowsums via atomicAdd RS[8192].
//
// Pipeline:
//   k0: transpose+cvt  X -> XT bf16 [512][8192],  W -> WT bf16 [256][512]
//   memset Sacc+RS = 0
//   k1: grid 1024 (64 rb x 4 cb x 4 ks): Sacc += A_slice @ X_slice (f32 atomics),
//       RS[row] += partial rowsum|A|
//   k2: combine: Sb = bf16(Sacc * 1/max(RS,eps))   (Sb aliases XT, dead by then)
//   k3: out = Sb @ W + bias  (f32)
// ws: XT @0 (8 MiB) | WT @8 MiB (256 KiB) | Sacc @8.25 MiB (16 MiB) | RS (32 KiB)
//     total 24.3 MiB  (< 25.5 MiB proven in R2)

typedef __attribute__((ext_vector_type(8))) __bf16 bf16x8;
typedef __attribute__((ext_vector_type(4))) float f32x4;

#define AS1 __attribute__((address_space(1)))
#define AS3 __attribute__((address_space(3)))

__device__ __forceinline__ void async_load16(const void* g, void* l) {
  __builtin_amdgcn_global_load_lds((const AS1 void*)g, (AS3 void*)l, 16, 0, 0);
}

// ---------------- kernel 0: 64x64 tiled transpose + f32->bf16 ----------------
__global__ __launch_bounds__(256) void transpose_cvt_kernel(
    const float* __restrict__ src, __hip_bfloat16* __restrict__ dst, int R, int C) {
  __shared__ float tile[64][65];
  const int t = threadIdx.x;
  const int nrb = R >> 6;
  const int rb = blockIdx.x % nrb, cb = blockIdx.x / nrb;
  const int r0 = rb * 64, c0 = cb * 64;
  const int lr = t >> 4, lc4 = (t & 15) * 4;
#pragma unroll
  for (int p = 0; p < 4; ++p) {
    const int r = p * 16 + lr;
    const f32x4 v = *(const f32x4*)(src + (size_t)(r0 + r) * C + c0 + lc4);
    tile[r][lc4 + 0] = v[0]; tile[r][lc4 + 1] = v[1];
    tile[r][lc4 + 2] = v[2]; tile[r][lc4 + 3] = v[3];
  }
  __syncthreads();
#pragma unroll
  for (int i = 0; i < 16; ++i) {
    const int idx = i * 256 + t;
    const int n = idx >> 6, k = idx & 63;
    dst[(size_t)(c0 + n) * R + r0 + k] = __float2bfloat16(tile[k][n]);
  }
}

// ---------------- kernel 1: split-K x4, BK=32, atomic f32 accumulation ----------------
// BM=128, BN=128, BK=32, 256 threads (4 waves 2x2), wave-tile 64x64 (4x4 MFMA tiles)
// grid 1024 = 64 rb x 4 cb x 4 ks -> 4 blocks/CU (LDS 32KB, VGPR<=128)
__global__ __launch_bounds__(256, 4) void gemm1_kernel(
    const float* __restrict__ A,            // [8192][8192]
    const __hip_bfloat16* __restrict__ XT,  // [512][8192]
    float* __restrict__ Sacc,               // [8192][512] f32 (zeroed)
    float* __restrict__ RS)                 // [8192] f32 (zeroed)
{
  __shared__ char smem[32768];
  char* Abase = smem;             // [2][128 rows][64 B], chunk P = kq ^ (row&3)
  char* Xbase = smem + 16384;     // [2][128 n   ][64 B], chunk G = kq ^ (n&3)
  float* rsmem = (float*)Xbase;   // aliases Xbuf[0]; last compute (kt=63) uses buf1

  const int t = threadIdx.x;
  const int wave = t >> 6, lane = t & 63;
  const int quad = lane >> 4, l16 = lane & 15;

  // XCD swizzle: all 16 (cb,ks) siblings of an rb-group share an XCD -> A L2 reuse
  const int b = blockIdx.x;
  const int xcd = b & 7, s = b >> 3;          // s in 0..127
  const int rb = xcd * 8 + (s >> 4);          // 0..63
  const int cb = s & 3;                       // 0..3
  const int ks = (s >> 2) & 3;                // 0..3
  const int r0 = rb * 128, c0 = cb * 128;
  const int k0 = ks * 2048;

  const int wm = wave & 1, wn = wave >> 1;

  f32x4 acc[4][4] = {};
  float rs = 0.0f;

  // A staging: thread -> row am = t>>1, k-half (t&1)*16 floats (64 B / iter)
  const int am = t >> 1;
  const int akq = (t & 1) * 2;  // first bf16-chunk index (chunk = 8 bf16 = 16 B)
  const float* ap = A + (size_t)(r0 + am) * 8192 + k0 + (t & 1) * 16;
  char* aw_base = Abase + am * 64;

  f32x4 areg[4];
#pragma unroll
  for (int i = 0; i < 4; ++i) areg[i] = *(const f32x4*)(ap + i * 4);

  // X prologue (kt=0 -> buf0): 8 KB = 512 slots of 16 B
#pragma unroll
  for (int i = 0; i < 2; ++i) {
    const int slot = i * 256 + t;
    const int n = slot >> 2;
    const int G = (slot & 3) ^ (n & 3);
    async_load16(XT + (size_t)(c0 + n) * 8192 + k0 + G * 8, Xbase + slot * 16);
  }

  int cur = 0;
#pragma unroll 2
  for (int kt = 0; kt < 64; ++kt) {
    {  // stage A(kt): rowsum + cvt + swizzled ds_write_b128 (2 per thread)
      char* aw = aw_base + cur * 8192;
#pragma unroll
      for (int i = 0; i < 2; ++i) {
        const f32x4 e = areg[i * 2], o = areg[i * 2 + 1];
        rs += fabsf(e[0]) + fabsf(e[1]) + fabsf(e[2]) + fabsf(e[3]) +
              fabsf(o[0]) + fabsf(o[1]) + fabsf(o[2]) + fabsf(o[3]);
        bf16x8 v;
        v[0] = (__bf16)e[0]; v[1] = (__bf16)e[1]; v[2] = (__bf16)e[2]; v[3] = (__bf16)e[3];
        v[4] = (__bf16)o[0]; v[5] = (__bf16)o[1]; v[6] = (__bf16)o[2]; v[7] = (__bf16)o[3];
        const int P = (akq + i) ^ (am & 3);
        *(bf16x8*)(aw + P * 16) = v;
      }
    }
    __syncthreads();

    if (kt < 63) {  // prefetch kt+1
      const float* apk = ap + (kt + 1) * 32;
#pragma unroll
      for (int i = 0; i < 4; ++i) areg[i] = *(const f32x4*)(apk + i * 4);
#pragma unroll
      for (int i = 0; i < 2; ++i) {
        const int slot = i * 256 + t;
        const int n = slot >> 2;
        const int G = (slot & 3) ^ (n & 3);
        async_load16(XT + (size_t)(c0 + n) * 8192 + k0 + (kt + 1) * 32 + G * 8,
                     Xbase + (cur ^ 1) * 8192 + slot * 16);
      }
    }

    {  // compute: 8 ds_read_b128 + 16 MFMA per wave
      const char* ab = Abase + cur * 8192;
      const char* xb = Xbase + cur * 8192;
      bf16x8 af[4];
#pragma unroll
      for (int rt = 0; rt < 4; ++rt) {
        const int row = wm * 64 + rt * 16 + l16;
        const int ch = quad ^ (row & 3);
        af[rt] = *(const bf16x8*)(ab + row * 64 + ch * 16);
      }
#pragma unroll
      for (int ct = 0; ct < 4; ++ct) {
        const int nrow = wn * 64 + ct * 16 + l16;
        const int ch = quad ^ (nrow & 3);
        const bf16x8 bfr = *(const bf16x8*)(xb + nrow * 64 + ch * 16);
#pragma unroll
        for (int rt = 0; rt < 4; ++rt)
          acc[rt][ct] = __builtin_amdgcn_mfma_f32_16x16x32_bf16(
              af[rt], bfr, acc[rt][ct], 0, 0, 0);
      }
    }
    cur ^= 1;
  }

  // epilogue: rowsum reduce (thread pairs) + atomic accumulate
  rsmem[t] = rs;  // buf0 region; compute(63) used buf1
  __syncthreads();
  if (cb == 0 && t < 128) {
    atomicAdd(&RS[r0 + t], rsmem[2 * t] + rsmem[2 * t + 1]);
  }
#pragma unroll
  for (int rt = 0; rt < 4; ++rt) {
#pragma unroll
    for (int r = 0; r < 4; ++r) {
      const int row_l = wm * 64 + rt * 16 + quad * 4 + r;  // C/D: row=(lane>>4)*4+reg
#pragma unroll
      for (int ct = 0; ct < 4; ++ct) {
        const int col_l = wn * 64 + ct * 16 + l16;         // C/D: col=lane&15
        atomicAdd(&Sacc[(size_t)(r0 + row_l) * 512 + c0 + col_l], acc[rt][ct][r]);
      }
    }
  }
}

// ---------------- kernel 2: combine -> normalized S (bf16) ----------------
__global__ __launch_bounds__(256) void combine_kernel(
    const float* __restrict__ Sacc, const float* __restrict__ RS,
    __hip_bfloat16* __restrict__ Sb) {
  const int idx = blockIdx.x * 256 + threadIdx.x;  // 8 cols per thread
  const int row = idx >> 6;
  const int c = (idx & 63) * 8;
  const float inv = 1.0f / fmaxf(RS[row], 1e-12f);
  const size_t off = (size_t)row * 512 + c;
  const f32x4 a = *(const f32x4*)(Sacc + off);
  const f32x4 d = *(const f32x4*)(Sacc + off + 4);
  bf16x8 o;
  o[0] = (__bf16)(a[0] * inv); o[1] = (__bf16)(a[1] * inv);
  o[2] = (__bf16)(a[2] * inv); o[3] = (__bf16)(a[3] * inv);
  o[4] = (__bf16)(d[0] * inv); o[5] = (__bf16)(d[1] * inv);
  o[6] = (__bf16)(d[2] * inv); o[7] = (__bf16)(d[3] * inv);
  *(bf16x8*)(Sb + off) = o;
}

// ---------------- kernel 3: out = S @ W + bias ----------------
__global__ __launch_bounds__(256) void gemm2_kernel(
    const __hip_bfloat16* __restrict__ Sb,  // [8192][512]
    const __hip_bfloat16* __restrict__ WT,  // [256][512]
    const float* __restrict__ bias,         // [256]
    float* __restrict__ Out)                // [8192][256]
{
  __shared__ char smem[49152];
  char* Sbase = smem;            // [2][64][128B]
  char* Wbase = smem + 16384;    // [2][128][128B]

  const int t = threadIdx.x;
  const int wave = t >> 6, lane = t & 63;
  const int quad = lane >> 4, l16 = lane & 15;

  const int b = blockIdx.x;
  const int xcd = b & 7, s = b >> 3;
  const int rb = xcd * 16 + (s >> 1), cb = s & 1;
  const int r0 = rb * 64, c0 = cb * 128;

  const int wm = wave & 1, wn = wave >> 1;

  f32x4 acc[2][4] = {};

  auto issue = [&](int buf, int kt) {
#pragma unroll
    for (int i = 0; i < 2; ++i) {
      const int slot = i * 256 + t;
      const int m = slot >> 3;
      const int G = (slot & 7) ^ (m & 7);
      async_load16(Sb + (size_t)(r0 + m) * 512 + kt * 64 + G * 8,
                   Sbase + buf * 8192 + slot * 16);
    }
#pragma unroll
    for (int i = 0; i < 4; ++i) {
      const int slot = i * 256 + t;
      const int n = slot >> 3;
      const int G = (slot & 7) ^ (n & 7);
      async_load16(WT + (size_t)(c0 + n) * 512 + kt * 64 + G * 8,
                   Wbase + buf * 16384 + slot * 16);
    }
  };

  issue(0, 0);
  int cur = 0;
#pragma unroll 2
  for (int kt = 0; kt < 8; ++kt) {
    __syncthreads();
    if (kt < 7) issue(cur ^ 1, kt + 1);
    const char* sb = Sbase + cur * 8192;
    const char* wb = Wbase + cur * 16384;
    bf16x8 af[2][2];
#pragma unroll
    for (int rt = 0; rt < 2; ++rt) {
      const int row = wm * 32 + rt * 16 + l16;
#pragma unroll
      for (int kb = 0; kb < 2; ++kb) {
        const int ch = (kb * 4 + quad) ^ (row & 7);
        af[rt][kb] = *(const bf16x8*)(sb + row * 128 + ch * 16);
      }
    }
#pragma unroll
    for (int ct = 0; ct < 4; ++ct) {
      const int nrow = wn * 64 + ct * 16 + l16;
#pragma unroll
      for (int kb = 0; kb < 2; ++kb) {
        const int ch = (kb * 4 + quad) ^ (nrow & 7);
        const bf16x8 bfr = *(const bf16x8*)(wb + nrow * 128 + ch * 16);
#pragma unroll
        for (int rt = 0; rt < 2; ++rt)
          acc[rt][ct] = __builtin_amdgcn_mfma_f32_16x16x32_bf16(
              af[rt][kb], bfr, acc[rt][ct], 0, 0, 0);
      }
    }
    cur ^= 1;
  }

#pragma unroll
  for (int rt = 0; rt < 2; ++rt) {
#pragma unroll
    for (int r = 0; r < 4; ++r) {
      const int row_l = wm * 32 + rt * 16 + quad * 4 + r;
#pragma unroll
      for (int ct = 0; ct < 4; ++ct) {
        const int col_l = wn * 64 + ct * 16 + l16;
        Out[(size_t)(r0 + row_l) * 256 + c0 + col_l] =
            acc[rt][ct][r] + bias[c0 + col_l];
      }
    }
  }
}

extern "C" void kernel_launch(void* const* d_in, const int* in_sizes, int n_in,
                              void* d_out, int out_size, void* d_ws, size_t ws_size,
                              hipStream_t stream) {
  const float* A    = (const float*)d_in[0];
  const float* Xf   = (const float*)d_in[1];
  const float* Wf   = (const float*)d_in[2];
  const float* bias = (const float*)d_in[3];
  float* Out = (float*)d_out;

  char* ws = (char*)d_ws;  // 24.3 MiB
  __hip_bfloat16* XT   = (__hip_bfloat16*)ws;                    // [512][8192]  8 MiB
  __hip_bfloat16* WT   = (__hip_bfloat16*)(ws + 8388608);        // [256][512]   256 KiB
  float*          Sacc = (float*)(ws + 8650752);                 // [8192][512]  16 MiB
  float*          RS   = (float*)(ws + 25427968);                // [8192]       32 KiB
  __hip_bfloat16* Sb   = (__hip_bfloat16*)ws;  // aliases XT (dead after gemm1)

  transpose_cvt_kernel<<<1024, 256, 0, stream>>>(Xf, XT, 8192, 512);
  transpose_cvt_kernel<<<32, 256, 0, stream>>>(Wf, WT, 512, 256);
  hipMemsetAsync(Sacc, 0, 16777216 + 32768, stream);  // Sacc + RS
  gemm1_kernel<<<1024, 256, 0, stream>>>(A, XT, Sacc, RS);
  combine_kernel<<<2048, 256, 0, stream>>>(Sacc, RS, Sb);
  gemm2_kernel<<<256, 256, 0, stream>>>(Sb, WT, bias, Out);
}

// Round 4
// 502.058 us; speedup vs baseline: 1.0958x; 1.0245x over previous
//
#include <hip/hip_runtime.h>
#include <hip/hip_bf16.h>

// MessagePassing: out = (A / rowsum|A|) @ X @ W + b
//   A [8192,8192] f32, X [8192,512] f32, W [512,256] f32, b [256] f32 -> out [8192,256] f32
//
// R3 post-mortem: per-CU VMEM pinned at ~12 B/cyc across R1-R3 regardless of
// occupancy -> time == logical L1-miss bytes / (256 CU * 12 B/cyc). R4 cuts
// logical bytes 1.5 GB -> 0.85 GB via fat tile BM=256,BN=256 (1024 thr, 16
// waves), plus row-pair LDS swizzle (R3's BK=32 layout caused 1.26e7 conflicts).
//
// Pipeline:
//   k0: transpose+cvt  X -> XT bf16 [512][8192],  W -> WT bf16 [256][512]
//   memset Sacc+RS = 0
//   k1: grid 256 (32 rb x 2 cb x 4 ks): Sacc += A_slice @ X_slice (f32 atomics),
//       RS[row] += partial rowsum|A|
//   k2: out = (Sacc * 1/max(RS,eps)) @ W + bias   (combine fused into staging)
// ws: XT @0 (8 MiB) | WT @8 MiB (256 KiB) | Sacc @8.25 MiB (16 MiB) | RS (32 KiB)

typedef __attribute__((ext_vector_type(8))) __bf16 bf16x8;
typedef __attribute__((ext_vector_type(4))) float f32x4;

#define AS1 __attribute__((address_space(1)))
#define AS3 __attribute__((address_space(3)))

__device__ __forceinline__ void async_load16(const void* g, void* l) {
  __builtin_amdgcn_global_load_lds((const AS1 void*)g, (AS3 void*)l, 16, 0, 0);
}

// ---------------- kernel 0: 64x64 tiled transpose + f32->bf16 ----------------
__global__ __launch_bounds__(256) void transpose_cvt_kernel(
    const float* __restrict__ src, __hip_bfloat16* __restrict__ dst, int R, int C) {
  __shared__ float tile[64][65];
  const int t = threadIdx.x;
  const int nrb = R >> 6;
  const int rb = blockIdx.x % nrb, cb = blockIdx.x / nrb;
  const int r0 = rb * 64, c0 = cb * 64;
  const int lr = t >> 4, lc4 = (t & 15) * 4;
#pragma unroll
  for (int p = 0; p < 4; ++p) {
    const int r = p * 16 + lr;
    const f32x4 v = *(const f32x4*)(src + (size_t)(r0 + r) * C + c0 + lc4);
    tile[r][lc4 + 0] = v[0]; tile[r][lc4 + 1] = v[1];
    tile[r][lc4 + 2] = v[2]; tile[r][lc4 + 3] = v[3];
  }
  __syncthreads();
#pragma unroll
  for (int i = 0; i < 16; ++i) {
    const int idx = i * 256 + t;
    const int n = idx >> 6, k = idx & 63;
    dst[(size_t)(c0 + n) * R + r0 + k] = __float2bfloat16(tile[k][n]);
  }
}

// ---------------- kernel 1: fat-tile split-K GEMM, atomic f32 accumulation ----------------
// BM=256, BN=256, BK=32, 1024 threads (16 waves 4x4), wave-tile 64x64.
// grid 256 = 32 rb x 2 cb x 4 ks -> 1 block/CU, 16 waves (VGPR-full).
// LDS row-pair swizzle: logical chunk c (16B) of row r lives at
//   (r>>1)*128 + (((c + 4*(r&1)) ^ ((r>>1)&7)) * 16
// -> consecutive-8-lane octets in ds_read_b128/ds_write_b128 hit 8 distinct
//    bank groups (conflict-free; R3's 64B-row layout was 2-way conflicted).
__global__ __launch_bounds__(1024, 4) void gemm1_kernel(
    const float* __restrict__ A,            // [8192][8192]
    const __hip_bfloat16* __restrict__ XT,  // [512][8192]
    float* __restrict__ Sacc,               // [8192][512] f32 (zeroed)
    float* __restrict__ RS)                 // [8192] f32 (zeroed)
{
  __shared__ char smem[65536];
  char* Abase = smem;             // [2][128 row-pairs][128 B]
  char* Xbase = smem + 32768;     // [2][128 col-pairs][128 B]
  float* rsmem = (float*)Xbase;   // aliases Xbuf[0]; compute(63) uses buf1

  const int t = threadIdx.x;
  const int wave = t >> 6, lane = t & 63;
  const int quad = lane >> 4, l16 = lane & 15;

  // XCD map: xcd = (ks<<1)|cb -> per-XCD X slice = 256 cols x 2048 K x 2B = 1 MB
  // (L2-resident); A ks-slices shared across the 2 cb-XCDs via L3.
  const int b = blockIdx.x;
  const int xcd = b & 7;
  const int cb = xcd & 1, ks = xcd >> 1;
  const int rb = b >> 3;                    // 0..31
  const int r0 = rb * 256, c0 = cb * 256;
  const int k0 = ks * 2048;

  const int wm = wave & 3, wn = wave >> 2;

  f32x4 acc[4][4] = {};
  float rs = 0.0f;

  // A staging: thread -> row am = t>>2 (256 rows), k-quarter (t&3)*8 floats
  const int am = t >> 2;
  const int kc = t & 3;  // logical 16B-chunk index within BK=32
  const float* ap = A + (size_t)(r0 + am) * 8192 + k0 + kc * 8;
  // swizzled write offset (constant per thread)
  const int aw_off = (am >> 1) * 128 + (((kc + 4 * (am & 1)) ^ ((am >> 1) & 7)) * 16);

  f32x4 areg[2];
  areg[0] = *(const f32x4*)(ap);
  areg[1] = *(const f32x4*)(ap + 4);

  // X prologue (kt=0 -> buf0): 1024 slots of 16 B, source-address inverse swizzle
  {
    const int q = t >> 3;
    const int u = (t & 7) ^ (q & 7);
    const int n = 2 * q + (u >> 2), g = u & 3;
    async_load16(XT + (size_t)(c0 + n) * 8192 + k0 + g * 8, Xbase + t * 16);
  }

  int cur = 0;
#pragma unroll 2
  for (int kt = 0; kt < 64; ++kt) {
    {  // stage A(kt): rowsum + cvt + one swizzled ds_write_b128
      const f32x4 e = areg[0], o = areg[1];
      rs += fabsf(e[0]) + fabsf(e[1]) + fabsf(e[2]) + fabsf(e[3]) +
            fabsf(o[0]) + fabsf(o[1]) + fabsf(o[2]) + fabsf(o[3]);
      bf16x8 v;
      v[0] = (__bf16)e[0]; v[1] = (__bf16)e[1]; v[2] = (__bf16)e[2]; v[3] = (__bf16)e[3];
      v[4] = (__bf16)o[0]; v[5] = (__bf16)o[1]; v[6] = (__bf16)o[2]; v[7] = (__bf16)o[3];
      *(bf16x8*)(Abase + cur * 16384 + aw_off) = v;
    }
    __syncthreads();

    if (kt < 63) {  // prefetch kt+1
      const float* apk = ap + (kt + 1) * 32;
      areg[0] = *(const f32x4*)(apk);
      areg[1] = *(const f32x4*)(apk + 4);
      const int q = t >> 3;
      const int u = (t & 7) ^ (q & 7);
      const int n = 2 * q + (u >> 2), g = u & 3;
      async_load16(XT + (size_t)(c0 + n) * 8192 + k0 + (kt + 1) * 32 + g * 8,
                   Xbase + (cur ^ 1) * 16384 + t * 16);
    }

    {  // compute: 8 ds_read_b128 + 16 MFMA per wave
      const char* ab = Abase + cur * 16384;
      const char* xb = Xbase + cur * 16384;
      bf16x8 af[4];
#pragma unroll
      for (int rt = 0; rt < 4; ++rt) {
        const int row = wm * 64 + rt * 16 + l16;
        const int off = (row >> 1) * 128 + (((quad + 4 * (row & 1)) ^ ((row >> 1) & 7)) * 16);
        af[rt] = *(const bf16x8*)(ab + off);
      }
#pragma unroll
      for (int ct = 0; ct < 4; ++ct) {
        const int n = wn * 64 + ct * 16 + l16;
        const int off = (n >> 1) * 128 + (((quad + 4 * (n & 1)) ^ ((n >> 1) & 7)) * 16);
        const bf16x8 bfr = *(const bf16x8*)(xb + off);
#pragma unroll
        for (int rt = 0; rt < 4; ++rt)
          acc[rt][ct] = __builtin_amdgcn_mfma_f32_16x16x32_bf16(
              af[rt], bfr, acc[rt][ct], 0, 0, 0);
      }
    }
    cur ^= 1;
  }

  // epilogue: rowsum reduce (4 threads per row) + atomic accumulate
  rsmem[t] = rs;  // Xbuf0 region; compute(63) used buf1
  __syncthreads();
  if (cb == 0 && t < 256) {
    atomicAdd(&RS[r0 + t],
              rsmem[4 * t] + rsmem[4 * t + 1] + rsmem[4 * t + 2] + rsmem[4 * t + 3]);
  }
#pragma unroll
  for (int rt = 0; rt < 4; ++rt) {
#pragma unroll
    for (int r = 0; r < 4; ++r) {
      const int row_l = wm * 64 + rt * 16 + quad * 4 + r;  // C/D: row=(lane>>4)*4+reg
#pragma unroll
      for (int ct = 0; ct < 4; ++ct) {
        const int col_l = wn * 64 + ct * 16 + l16;         // C/D: col=lane&15
        atomicAdd(&Sacc[(size_t)(r0 + row_l) * 512 + c0 + col_l], acc[rt][ct][r]);
      }
    }
  }
}

// ---------------- kernel 2: out = (Sacc/RS) @ W + bias (combine fused) ----------------
// BM=64, BN=128, BK=64, 256 threads (4 waves 2x2), wave-tile 32x64, 8 K-iters.
// S staged from f32 Sacc through regs: normalize by 1/RS, cvt bf16, swizzled write.
__global__ __launch_bounds__(256) void gemm2_kernel(
    const float* __restrict__ Sacc,         // [8192][512] f32
    const float* __restrict__ RS,           // [8192]
    const __hip_bfloat16* __restrict__ WT,  // [256][512]
    const float* __restrict__ bias,         // [256]
    float* __restrict__ Out)                // [8192][256]
{
  __shared__ char smem[49152];
  char* Sbase = smem;            // [2][64 rows][128 B], chunk P = c ^ (row&7)
  char* Wbase = smem + 16384;    // [2][128 n  ][128 B], chunk P = c ^ (n&7)

  const int t = threadIdx.x;
  const int wave = t >> 6, lane = t & 63;
  const int quad = lane >> 4, l16 = lane & 15;

  const int b = blockIdx.x;
  const int xcd = b & 7, s = b >> 3;
  const int rb = xcd * 16 + (s >> 1), cb = s & 1;
  const int r0 = rb * 64, c0 = cb * 128;

  const int wm = wave & 1, wn = wave >> 1;

  f32x4 acc[2][4] = {};

  // S staging: thread -> row am = t>>2 (64 rows), k-quarter (t&3)*16 floats
  const int am = t >> 2;
  const int kq = t & 3;
  const float* sp = Sacc + (size_t)(r0 + am) * 512 + kq * 16;
  const float inv = 1.0f / fmaxf(RS[r0 + am], 1e-12f);
  const int sw0 = am * 128 + (((kq * 2 + 0) ^ (am & 7)) * 16);
  const int sw1 = am * 128 + (((kq * 2 + 1) ^ (am & 7)) * 16);

  f32x4 sreg[4];
#pragma unroll
  for (int i = 0; i < 4; ++i) sreg[i] = *(const f32x4*)(sp + i * 4);

  // W prologue (kt=0 -> buf0)
#pragma unroll
  for (int i = 0; i < 4; ++i) {
    const int slot = i * 256 + t;
    const int n = slot >> 3;
    const int G = (slot & 7) ^ (n & 7);
    async_load16(WT + (size_t)(c0 + n) * 512 + G * 8, Wbase + slot * 16);
  }

  int cur = 0;
#pragma unroll 2
  for (int kt = 0; kt < 8; ++kt) {
    {  // stage S(kt): normalize, cvt, 2 swizzled ds_write_b128
      char* sw = Sbase + cur * 8192;
      bf16x8 v0, v1;
#pragma unroll
      for (int j = 0; j < 4; ++j) {
        v0[j]     = (__bf16)(sreg[0][j] * inv);
        v0[j + 4] = (__bf16)(sreg[1][j] * inv);
        v1[j]     = (__bf16)(sreg[2][j] * inv);
        v1[j + 4] = (__bf16)(sreg[3][j] * inv);
      }
      *(bf16x8*)(sw + sw0) = v0;
      *(bf16x8*)(sw + sw1) = v1;
    }
    __syncthreads();

    if (kt < 7) {  // prefetch kt+1
      const float* spk = sp + (kt + 1) * 64;
#pragma unroll
      for (int i = 0; i < 4; ++i) sreg[i] = *(const f32x4*)(spk + i * 4);
#pragma unroll
      for (int i = 0; i < 4; ++i) {
        const int slot = i * 256 + t;
        const int n = slot >> 3;
        const int G = (slot & 7) ^ (n & 7);
        async_load16(WT + (size_t)(c0 + n) * 512 + (kt + 1) * 64 + G * 8,
                     Wbase + (cur ^ 1) * 16384 + slot * 16);
      }
    }

    {  // compute: 12 ds_read_b128 + 16 MFMA per wave
      const char* sb = Sbase + cur * 8192;
      const char* wb = Wbase + cur * 16384;
      bf16x8 af[2][2];
#pragma unroll
      for (int rt = 0; rt < 2; ++rt) {
        const int row = wm * 32 + rt * 16 + l16;
#pragma unroll
        for (int kb = 0; kb < 2; ++kb) {
          const int ch = (kb * 4 + quad) ^ (row & 7);
          af[rt][kb] = *(const bf16x8*)(sb + row * 128 + ch * 16);
        }
      }
#pragma unroll
      for (int ct = 0; ct < 4; ++ct) {
        const int n = wn * 64 + ct * 16 + l16;
#pragma unroll
        for (int kb = 0; kb < 2; ++kb) {
          const int ch = (kb * 4 + quad) ^ (n & 7);
          const bf16x8 bfr = *(const bf16x8*)(wb + n * 128 + ch * 16);
#pragma unroll
          for (int rt = 0; rt < 2; ++rt)
            acc[rt][ct] = __builtin_amdgcn_mfma_f32_16x16x32_bf16(
                af[rt][kb], bfr, acc[rt][ct], 0, 0, 0);
        }
      }
    }
    cur ^= 1;
  }

#pragma unroll
  for (int rt = 0; rt < 2; ++rt) {
#pragma unroll
    for (int r = 0; r < 4; ++r) {
      const int row_l = wm * 32 + rt * 16 + quad * 4 + r;
#pragma unroll
      for (int ct = 0; ct < 4; ++ct) {
        const int col_l = wn * 64 + ct * 16 + l16;
        Out[(size_t)(r0 + row_l) * 256 + c0 + col_l] =
            acc[rt][ct][r] + bias[c0 + col_l];
      }
    }
  }
}

extern "C" void kernel_launch(void* const* d_in, const int* in_sizes, int n_in,
                              void* d_out, int out_size, void* d_ws, size_t ws_size,
                              hipStream_t stream) {
  const float* A    = (const float*)d_in[0];
  const float* Xf   = (const float*)d_in[1];
  const float* Wf   = (const float*)d_in[2];
  const float* bias = (const float*)d_in[3];
  float* Out = (float*)d_out;

  char* ws = (char*)d_ws;  // 24.3 MiB
  __hip_bfloat16* XT   = (__hip_bfloat16*)ws;                    // [512][8192]  8 MiB
  __hip_bfloat16* WT   = (__hip_bfloat16*)(ws + 8388608);        // [256][512]   256 KiB
  float*          Sacc = (float*)(ws + 8650752);                 // [8192][512]  16 MiB
  float*          RS   = (float*)(ws + 25427968);                // [8192]       32 KiB

  transpose_cvt_kernel<<<1024, 256, 0, stream>>>(Xf, XT, 8192, 512);
  transpose_cvt_kernel<<<32, 256, 0, stream>>>(Wf, WT, 512, 256);
  hipMemsetAsync(Sacc, 0, 16777216 + 32768, stream);  // Sacc + RS
  gemm1_kernel<<<256, 1024, 0, stream>>>(A, XT, Sacc, RS);
  gemm2_kernel<<<256, 256, 0, stream>>>(Sacc, RS, WT, bias, Out);
}